// Round 7
// baseline (774.676 us; speedup 1.0000x reference)
//
#include <hip/hip_runtime.h>

#define DD 64
#define EPSV 1e-5f

__device__ __forceinline__ float rlane_f(float v, int k) {
    return __int_as_float(__builtin_amdgcn_readlane(__float_as_int(v), k));
}

// ---------------------------------------------------------------------------
// Detect whether edge_index is int64 or int32 (JAX x64 flag ambiguity).
// ---------------------------------------------------------------------------
__global__ void detect_idx_kernel(const void* __restrict__ idx, int* __restrict__ flag,
                                  int nsample, int n_nodes) {
    const long long* p = (const long long*)idx;
    int bad = 0;
    for (int i = threadIdx.x; i < nsample; i += blockDim.x) {
        long long v = p[i];
        if (v < 0 || v >= (long long)n_nodes) bad = 1;
    }
    __shared__ int sbad;
    if (threadIdx.x == 0) sbad = 0;
    __syncthreads();
    if (bad) atomicOr(&sbad, 1);
    __syncthreads();
    if (threadIdx.x == 0) *flag = sbad ? 0 : 1;  // 1 => int64, 0 => int32
}

// ---------------------------------------------------------------------------
// CSR build: histogram -> scan -> fill
//   dir0 (mi): keyed by t=end,   payload (s=start, w)
//   dir1 (mo): keyed by s=start, payload (t=end, w)
// ---------------------------------------------------------------------------
__global__ __launch_bounds__(256) void hist_kernel(
    const void* __restrict__ idx, const int* __restrict__ flag,
    int* __restrict__ cnt0, int* __restrict__ cnt1, int n_edges) {
    const bool is64 = (*flag != 0);
    const long long* p64 = (const long long*)idx;
    const int*       p32 = (const int*)idx;
    int tid = blockIdx.x * blockDim.x + threadIdx.x;
    int stride = gridDim.x * blockDim.x;
    for (int ed = tid; ed < n_edges; ed += stride) {
        int s, t;
        if (is64) { s = (int)p64[ed]; t = (int)p64[n_edges + ed]; }
        else      { s = p32[ed];      t = p32[n_edges + ed]; }
        atomicAdd(&cnt0[t], 1);
        atomicAdd(&cnt1[s], 1);
    }
}

// One block per direction; 1024 threads scan n counts.
__global__ __launch_bounds__(1024) void scan_kernel(
    const int* __restrict__ cnt0, const int* __restrict__ cnt1,
    int* __restrict__ offs0, int* __restrict__ offs1,
    int* __restrict__ cur0, int* __restrict__ cur1, int n) {
    const int* cnt = blockIdx.x ? cnt1 : cnt0;
    int* offs = blockIdx.x ? offs1 : offs0;
    int* cur  = blockIdx.x ? cur1  : cur0;
    const int C = (n + 1023) >> 10;
    const int t = threadIdx.x;
    const int base = t * C;
    int m = n - base; if (m > C) m = C; if (m < 0) m = 0;

    int sum = 0;
    for (int i = 0; i < m; ++i) sum += cnt[base + i];

    const int lane = t & 63, wid = t >> 6;
    int s = sum;
    #pragma unroll
    for (int d = 1; d < 64; d <<= 1) { int u = __shfl_up(s, d, 64); if (lane >= d) s += u; }

    __shared__ int wtot[16];
    if (lane == 63) wtot[wid] = s;
    __syncthreads();
    if (t < 16) {
        int w = wtot[t];
        int sw = w;
        #pragma unroll
        for (int d = 1; d < 16; d <<= 1) { int u = __shfl_up(sw, d, 64); if (t >= d) sw += u; }
        wtot[t] = sw - w;  // exclusive
    }
    __syncthreads();

    int run = wtot[wid] + (s - sum);
    for (int i = 0; i < m; ++i) {
        offs[base + i] = run;
        cur[base + i]  = run;
        run += cnt[base + i];
    }
    if (m > 0 && base + m == n) offs[n] = run;
}

__global__ __launch_bounds__(256) void fill_kernel(
    const void* __restrict__ idx, const float* __restrict__ e, const int* __restrict__ flag,
    int* __restrict__ cur0, int* __restrict__ cur1,
    int2* __restrict__ pay0, int2* __restrict__ pay1, int n_edges) {
    const bool is64 = (*flag != 0);
    const long long* p64 = (const long long*)idx;
    const int*       p32 = (const int*)idx;
    int tid = blockIdx.x * blockDim.x + threadIdx.x;
    int stride = gridDim.x * blockDim.x;
    for (int ed = tid; ed < n_edges; ed += stride) {
        int s, t;
        if (is64) { s = (int)p64[ed]; t = (int)p64[n_edges + ed]; }
        else      { s = p32[ed];      t = p32[n_edges + ed]; }
        int wbits = __float_as_int(e[ed]);
        int p0 = atomicAdd(&cur0[t], 1);
        pay0[p0] = make_int2(s, wbits);
        int p1 = atomicAdd(&cur1[s], 1);
        pay1[p1] = make_int2(t, wbits);
    }
}

// ---------------------------------------------------------------------------
// Gather: one wave per (node, dir). Payload batch-loaded coalesced, broadcast
// via v_readlane; x rows gathered as coalesced 256B reads; no atomics.
// ---------------------------------------------------------------------------
__global__ __launch_bounds__(256) void gather_kernel(
    const float* __restrict__ x,
    const int2* __restrict__ pay0, const int2* __restrict__ pay1,
    const int* __restrict__ offs0, const int* __restrict__ offs1,
    float* __restrict__ mi, float* __restrict__ mo, int n) {
    const int wid = threadIdx.x >> 6, lane = threadIdx.x & 63;
    const int gid = blockIdx.x * 4 + wid;
    if (gid >= 2 * n) return;
    const int dir = gid & 1, node = gid >> 1;
    const int* offs = dir ? offs1 : offs0;
    const int2* pay = dir ? pay1 : pay0;
    float* dst = dir ? mo : mi;

    const int o0 = offs[node], o1 = offs[node + 1];
    float acc = 0.0f;
    for (int b = o0; b < o1; b += 64) {
        int2 pl = make_int2(0, 0);
        if (b + lane < o1) pl = pay[b + lane];
        const int cnt = min(64, o1 - b);
        #pragma unroll 4
        for (int j = 0; j < cnt; ++j) {
            int src  = __builtin_amdgcn_readlane(pl.x, j);
            float w  = __int_as_float(__builtin_amdgcn_readlane(pl.y, j));
            acc = fmaf(w, x[src * DD + lane], acc);
        }
    }
    dst[node * DD + lane] = acc;
}

// ---------------------------------------------------------------------------
// Fallback atomic scatter (used only if ws too small for CSR).
// ---------------------------------------------------------------------------
__global__ __launch_bounds__(256) void scatter_kernel(
    const float* __restrict__ x, const float* __restrict__ e,
    const void* __restrict__ idx, const int* __restrict__ flag,
    float* __restrict__ mi, float* __restrict__ mo, int n_edges) {
    const int lane  = threadIdx.x & 63;
    const int slot  = (blockIdx.x * blockDim.x + threadIdx.x) >> 6;
    const int nslot = (gridDim.x * blockDim.x) >> 6;
    const bool is64 = (*flag != 0);
    const long long* p64 = (const long long*)idx;
    const int*       p32 = (const int*)idx;
    for (int ed = slot; ed < n_edges; ed += nslot) {
        int s, t;
        if (is64) { s = (int)p64[ed]; t = (int)p64[n_edges + ed]; }
        else      { s = p32[ed];      t = p32[n_edges + ed]; }
        float w  = e[ed];
        unsafeAtomicAdd(&mi[t * DD + lane], w * x[s * DD + lane]);
        unsafeAtomicAdd(&mo[s * DD + lane], w * x[t * DD + lane]);
    }
}

// ---------------------------------------------------------------------------
// Fused 4-layer MLP v2: h in registers (broadcast via v_readlane), W
// transposed in LDS so each lane reads its column as ds_read_b128 (4 k/read).
// ---------------------------------------------------------------------------
#define NPW 12
#define MWAVES 16
#define WT1_STRIDE 196  // 192 + 4 floats pad (keeps 16B alignment)
#define WT_STRIDE  68   // 64 + 4

template<int N>
__device__ __forceinline__ void accum64(const float4* __restrict__ wp,
                                        const float (&h)[N], float (&acc)[N]) {
    #pragma unroll 2
    for (int kb = 0; kb < 16; ++kb) {
        float4 w4 = wp[kb];
        int k0 = kb << 2;
        #pragma unroll
        for (int m = 0; m < N; ++m) acc[m] = fmaf(w4.x, rlane_f(h[m], k0), acc[m]);
        #pragma unroll
        for (int m = 0; m < N; ++m) acc[m] = fmaf(w4.y, rlane_f(h[m], k0 + 1), acc[m]);
        #pragma unroll
        for (int m = 0; m < N; ++m) acc[m] = fmaf(w4.z, rlane_f(h[m], k0 + 2), acc[m]);
        #pragma unroll
        for (int m = 0; m < N; ++m) acc[m] = fmaf(w4.w, rlane_f(h[m], k0 + 3), acc[m]);
    }
}

__device__ __forceinline__ float ln_relu(float v, float g, float bt) {
    float s = v;
    #pragma unroll
    for (int off = 32; off; off >>= 1) s += __shfl_xor(s, off, 64);
    float mu = s * (1.0f / 64.0f);
    float d = v - mu;
    float s2 = d * d;
    #pragma unroll
    for (int off = 32; off; off >>= 1) s2 += __shfl_xor(s2, off, 64);
    float r = d * rsqrtf(s2 * (1.0f / 64.0f) + EPSV) * g + bt;
    return fmaxf(r, 0.0f);
}

__global__ __launch_bounds__(1024) void fused_mlp2(
    const float* __restrict__ mi, const float* __restrict__ mo, const float* __restrict__ x,
    const float* __restrict__ W1, const float* __restrict__ b1, const float* __restrict__ g1, const float* __restrict__ bt1,
    const float* __restrict__ W2, const float* __restrict__ b2, const float* __restrict__ g2, const float* __restrict__ bt2,
    const float* __restrict__ W3, const float* __restrict__ b3, const float* __restrict__ g3, const float* __restrict__ bt3,
    const float* __restrict__ W4, const float* __restrict__ b4, const float* __restrict__ g4, const float* __restrict__ bt4,
    float* __restrict__ out, int n_nodes) {

    __shared__ float sWT1[64 * WT1_STRIDE];
    __shared__ float sWT2[64 * WT_STRIDE];
    __shared__ float sWT3[64 * WT_STRIDE];
    __shared__ float sWT4[64 * WT_STRIDE];
    __shared__ float sB[4][3][64];

    const int tid = threadIdx.x;
    for (int i = tid; i < 192 * 64; i += 1024) {
        int k = i >> 6, j = i & 63;
        sWT1[j * WT1_STRIDE + k] = W1[i];
    }
    for (int i = tid; i < 64 * 64; i += 1024) {
        int k = i >> 6, j = i & 63;
        sWT2[j * WT_STRIDE + k] = W2[i];
        sWT3[j * WT_STRIDE + k] = W3[i];
        sWT4[j * WT_STRIDE + k] = W4[i];
    }
    if (tid < 64) {
        int j = tid;
        sB[0][0][j] = b1[j]; sB[0][1][j] = g1[j]; sB[0][2][j] = bt1[j];
        sB[1][0][j] = b2[j]; sB[1][1][j] = g2[j]; sB[1][2][j] = bt2[j];
        sB[2][0][j] = b3[j]; sB[2][1][j] = g3[j]; sB[2][2][j] = bt3[j];
        sB[3][0][j] = b4[j]; sB[3][1][j] = g4[j]; sB[3][2][j] = bt4[j];
    }
    __syncthreads();

    const int wid = tid >> 6, lane = tid & 63;
    const int gw = blockIdx.x * MWAVES + wid;
    const int nw = gridDim.x * MWAVES;
    const float4* wt1 = (const float4*)&sWT1[lane * WT1_STRIDE];
    const float4* wt2 = (const float4*)&sWT2[lane * WT_STRIDE];
    const float4* wt3 = (const float4*)&sWT3[lane * WT_STRIDE];
    const float4* wt4 = (const float4*)&sWT4[lane * WT_STRIDE];

    const int ngroups = (n_nodes + NPW - 1) / NPW;
    for (int grp = gw; grp < ngroups; grp += nw) {
        const int n0 = grp * NPW;

        float hmi[NPW], hmo[NPW], hx[NPW];
        #pragma unroll
        for (int m = 0; m < NPW; ++m) {
            int n = n0 + m; if (n >= n_nodes) n = n_nodes - 1;
            hmi[m] = mi[n * DD + lane];
            hmo[m] = mo[n * DD + lane];
            hx[m]  = x[n * DD + lane];
        }

        float acc[NPW], h[NPW];

        // layer 1 (192-k)
        {
            float bj = sB[0][0][lane];
            #pragma unroll
            for (int m = 0; m < NPW; ++m) acc[m] = bj;
            accum64(wt1 +  0, hmi, acc);
            accum64(wt1 + 16, hmo, acc);
            accum64(wt1 + 32, hx,  acc);
            float gj = sB[0][1][lane], btj = sB[0][2][lane];
            #pragma unroll
            for (int m = 0; m < NPW; ++m) h[m] = ln_relu(acc[m], gj, btj);
        }

        // layers 2..4 (64-k)
        const float4* wts[3] = { wt2, wt3, wt4 };
        #pragma unroll
        for (int l = 0; l < 3; ++l) {
            float bj = sB[l + 1][0][lane];
            #pragma unroll
            for (int m = 0; m < NPW; ++m) acc[m] = bj;
            accum64(wts[l], h, acc);
            float gj = sB[l + 1][1][lane], btj = sB[l + 1][2][lane];
            #pragma unroll
            for (int m = 0; m < NPW; ++m) h[m] = ln_relu(acc[m], gj, btj);
        }

        #pragma unroll
        for (int m = 0; m < NPW; ++m) {
            int n = n0 + m;
            if (n < n_nodes) out[n * DD + lane] = h[m];
        }
    }
}

// ---------------------------------------------------------------------------
extern "C" void kernel_launch(void* const* d_in, const int* in_sizes, int n_in,
                              void* d_out, int out_size, void* d_ws, size_t ws_size,
                              hipStream_t stream) {
    const float* x   = (const float*)d_in[0];
    const float* e   = (const float*)d_in[1];
    const void*  idx = d_in[2];
    const float* W1 = (const float*)d_in[3],  *b1 = (const float*)d_in[4],
               * g1 = (const float*)d_in[5],  *bt1 = (const float*)d_in[6];
    const float* W2 = (const float*)d_in[7],  *b2 = (const float*)d_in[8],
               * g2 = (const float*)d_in[9],  *bt2 = (const float*)d_in[10];
    const float* W3 = (const float*)d_in[11], *b3 = (const float*)d_in[12],
               * g3 = (const float*)d_in[13], *bt3 = (const float*)d_in[14];
    const float* W4 = (const float*)d_in[15], *b4 = (const float*)d_in[16],
               * g4 = (const float*)d_in[17], *bt4 = (const float*)d_in[18];
    float* out = (float*)d_out;

    const int n_nodes = in_sizes[0] / DD;   // 50000
    const int n_edges = in_sizes[1];        // 1000000

    // ws layout (floats): mi | mo | flag(+pad) | pay0 | pay1 | cnt0 | cnt1 | offs0 | offs1 | cur0 | cur1
    float* mi = (float*)d_ws;
    float* mo = mi + (size_t)n_nodes * DD;
    int*  flag = (int*)(mo + (size_t)n_nodes * DD);
    char* p = (char*)(flag + 2);  // 8B align
    int2* pay0 = (int2*)p;            p += (size_t)n_edges * sizeof(int2);
    int2* pay1 = (int2*)p;            p += (size_t)n_edges * sizeof(int2);
    int* cnt0  = (int*)p;             p += (size_t)n_nodes * 4;
    int* cnt1  = (int*)p;             p += (size_t)n_nodes * 4;
    int* offs0 = (int*)p;             p += (size_t)(n_nodes + 1) * 4;
    int* offs1 = (int*)p;             p += (size_t)(n_nodes + 1) * 4;
    int* cur0  = (int*)p;             p += (size_t)n_nodes * 4;
    int* cur1  = (int*)p;             p += (size_t)n_nodes * 4;
    const size_t need = (size_t)(p - (char*)d_ws);

    detect_idx_kernel<<<1, 256, 0, stream>>>(idx, flag, 4096, n_nodes);

    if (ws_size >= need) {
        // CSR path: histogram -> scan -> fill -> gather (no f32 atomics)
        hipMemsetAsync(cnt0, 0, (size_t)2 * n_nodes * 4, stream);  // cnt0|cnt1 contiguous
        hist_kernel<<<2048, 256, 0, stream>>>(idx, flag, cnt0, cnt1, n_edges);
        scan_kernel<<<2, 1024, 0, stream>>>(cnt0, cnt1, offs0, offs1, cur0, cur1, n_nodes);
        fill_kernel<<<2048, 256, 0, stream>>>(idx, e, flag, cur0, cur1, pay0, pay1, n_edges);
        const int nblocks = (2 * n_nodes + 3) / 4;
        gather_kernel<<<nblocks, 256, 0, stream>>>(x, pay0, pay1, offs0, offs1, mi, mo, n_nodes);
    } else {
        // fallback: atomic scatter
        hipMemsetAsync(d_ws, 0, (size_t)2 * n_nodes * DD * sizeof(float), stream);
        scatter_kernel<<<4096, 256, 0, stream>>>(x, e, idx, flag, mi, mo, n_edges);
    }

    fused_mlp2<<<256, 1024, 0, stream>>>(
        mi, mo, x,
        W1, b1, g1, bt1, W2, b2, g2, bt2, W3, b3, g3, bt3, W4, b4, g4, bt4,
        out, n_nodes);
}

// Round 8
// 714.770 us; speedup vs baseline: 1.0838x; 1.0838x over previous
//
#include <hip/hip_runtime.h>

#define DD 64
#define EPSV 1e-5f

__device__ __forceinline__ float rlane_f(float v, int k) {
    return __int_as_float(__builtin_amdgcn_readlane(__float_as_int(v), k));
}

// ---------------------------------------------------------------------------
// Detect whether edge_index is int64 or int32 (JAX x64 flag ambiguity).
// ---------------------------------------------------------------------------
__global__ void detect_idx_kernel(const void* __restrict__ idx, int* __restrict__ flag,
                                  int nsample, int n_nodes) {
    const long long* p = (const long long*)idx;
    int bad = 0;
    for (int i = threadIdx.x; i < nsample; i += blockDim.x) {
        long long v = p[i];
        if (v < 0 || v >= (long long)n_nodes) bad = 1;
    }
    __shared__ int sbad;
    if (threadIdx.x == 0) sbad = 0;
    __syncthreads();
    if (bad) atomicOr(&sbad, 1);
    __syncthreads();
    if (threadIdx.x == 0) *flag = sbad ? 0 : 1;  // 1 => int64, 0 => int32
}

// ---------------------------------------------------------------------------
// Edge scatter (proven 406 us in round 2): one 64-lane wave per edge.
//   mi[end]   += e * x[start]
//   mo[start] += e * x[end]
// Atomic-RMW bound (WRITE_SIZE = 500 MB); VALUBusy ~11%.
// ---------------------------------------------------------------------------
__global__ __launch_bounds__(256) void scatter_kernel(
    const float* __restrict__ x, const float* __restrict__ e,
    const void* __restrict__ idx, const int* __restrict__ flag,
    float* __restrict__ mi, float* __restrict__ mo, int n_edges) {
    const int lane  = threadIdx.x & 63;
    const int slot  = (blockIdx.x * blockDim.x + threadIdx.x) >> 6;
    const int nslot = (gridDim.x * blockDim.x) >> 6;
    const bool is64 = (*flag != 0);
    const long long* p64 = (const long long*)idx;
    const int*       p32 = (const int*)idx;

    for (int ed = slot; ed < n_edges; ed += nslot) {
        int s, t;
        if (is64) { s = (int)p64[ed]; t = (int)p64[n_edges + ed]; }
        else      { s = p32[ed];      t = p32[n_edges + ed]; }
        float w  = e[ed];
        float xs = x[s * DD + lane];
        float xt = x[t * DD + lane];
        unsafeAtomicAdd(&mi[t * DD + lane], w * xs);
        unsafeAtomicAdd(&mo[s * DD + lane], w * xt);
    }
}

// ---------------------------------------------------------------------------
// Fused 4-layer MLP v3: h in registers (broadcast via v_readlane), W
// transposed in LDS, lane j reads its column as ds_read_b128 (4 k/read).
// v2->v3: #pragma unroll 4 on the kb loop so 4 independent ds_read_b128 are
// in flight per wave (v2's unroll-2 left the 48 dependent FMAs stalled on
// ~120-cyc LDS latency at only 4 waves/SIMD -> VALUBusy 41%).
// ---------------------------------------------------------------------------
#define NPW 12
#define MWAVES 16
#define WT1_STRIDE 196  // 192+4 pad: lane stride 196 dwords == 4 mod 32 -> 2-way (free) on b128 reads
#define WT_STRIDE  68   // 64+4

template<int N>
__device__ __forceinline__ void accum64(const float4* __restrict__ wp,
                                        const float (&h)[N], float (&acc)[N]) {
    #pragma unroll 4
    for (int kb = 0; kb < 16; ++kb) {
        float4 w4 = wp[kb];
        int k0 = kb << 2;
        #pragma unroll
        for (int m = 0; m < N; ++m) acc[m] = fmaf(w4.x, rlane_f(h[m], k0), acc[m]);
        #pragma unroll
        for (int m = 0; m < N; ++m) acc[m] = fmaf(w4.y, rlane_f(h[m], k0 + 1), acc[m]);
        #pragma unroll
        for (int m = 0; m < N; ++m) acc[m] = fmaf(w4.z, rlane_f(h[m], k0 + 2), acc[m]);
        #pragma unroll
        for (int m = 0; m < N; ++m) acc[m] = fmaf(w4.w, rlane_f(h[m], k0 + 3), acc[m]);
    }
}

__device__ __forceinline__ float ln_relu(float v, float g, float bt) {
    float s = v;
    #pragma unroll
    for (int off = 32; off; off >>= 1) s += __shfl_xor(s, off, 64);
    float mu = s * (1.0f / 64.0f);
    float d = v - mu;
    float s2 = d * d;
    #pragma unroll
    for (int off = 32; off; off >>= 1) s2 += __shfl_xor(s2, off, 64);
    float r = d * rsqrtf(s2 * (1.0f / 64.0f) + EPSV) * g + bt;
    return fmaxf(r, 0.0f);
}

__global__ __launch_bounds__(1024) void fused_mlp3(
    const float* __restrict__ mi, const float* __restrict__ mo, const float* __restrict__ x,
    const float* __restrict__ W1, const float* __restrict__ b1, const float* __restrict__ g1, const float* __restrict__ bt1,
    const float* __restrict__ W2, const float* __restrict__ b2, const float* __restrict__ g2, const float* __restrict__ bt2,
    const float* __restrict__ W3, const float* __restrict__ b3, const float* __restrict__ g3, const float* __restrict__ bt3,
    const float* __restrict__ W4, const float* __restrict__ b4, const float* __restrict__ g4, const float* __restrict__ bt4,
    float* __restrict__ out, int n_nodes) {

    __shared__ float sWT1[64 * WT1_STRIDE];
    __shared__ float sWT2[64 * WT_STRIDE];
    __shared__ float sWT3[64 * WT_STRIDE];
    __shared__ float sWT4[64 * WT_STRIDE];
    __shared__ float sB[4][3][64];

    const int tid = threadIdx.x;
    for (int i = tid; i < 192 * 64; i += 1024) {
        int k = i >> 6, j = i & 63;
        sWT1[j * WT1_STRIDE + k] = W1[i];
    }
    for (int i = tid; i < 64 * 64; i += 1024) {
        int k = i >> 6, j = i & 63;
        sWT2[j * WT_STRIDE + k] = W2[i];
        sWT3[j * WT_STRIDE + k] = W3[i];
        sWT4[j * WT_STRIDE + k] = W4[i];
    }
    if (tid < 64) {
        int j = tid;
        sB[0][0][j] = b1[j]; sB[0][1][j] = g1[j]; sB[0][2][j] = bt1[j];
        sB[1][0][j] = b2[j]; sB[1][1][j] = g2[j]; sB[1][2][j] = bt2[j];
        sB[2][0][j] = b3[j]; sB[2][1][j] = g3[j]; sB[2][2][j] = bt3[j];
        sB[3][0][j] = b4[j]; sB[3][1][j] = g4[j]; sB[3][2][j] = bt4[j];
    }
    __syncthreads();

    const int wid = tid >> 6, lane = tid & 63;
    const int gw = blockIdx.x * MWAVES + wid;
    const int nw = gridDim.x * MWAVES;
    const float4* wt1 = (const float4*)&sWT1[lane * WT1_STRIDE];
    const float4* wt2 = (const float4*)&sWT2[lane * WT_STRIDE];
    const float4* wt3 = (const float4*)&sWT3[lane * WT_STRIDE];
    const float4* wt4 = (const float4*)&sWT4[lane * WT_STRIDE];

    const int ngroups = (n_nodes + NPW - 1) / NPW;
    for (int grp = gw; grp < ngroups; grp += nw) {
        const int n0 = grp * NPW;

        float hmi[NPW], hmo[NPW], hx[NPW];
        #pragma unroll
        for (int m = 0; m < NPW; ++m) {
            int n = n0 + m; if (n >= n_nodes) n = n_nodes - 1;
            hmi[m] = mi[n * DD + lane];
            hmo[m] = mo[n * DD + lane];
            hx[m]  = x[n * DD + lane];
        }

        float acc[NPW], h[NPW];

        // layer 1 (192-k)
        {
            float bj = sB[0][0][lane];
            #pragma unroll
            for (int m = 0; m < NPW; ++m) acc[m] = bj;
            accum64(wt1 +  0, hmi, acc);
            accum64(wt1 + 16, hmo, acc);
            accum64(wt1 + 32, hx,  acc);
            float gj = sB[0][1][lane], btj = sB[0][2][lane];
            #pragma unroll
            for (int m = 0; m < NPW; ++m) h[m] = ln_relu(acc[m], gj, btj);
        }

        // layers 2..4 (64-k)
        const float4* wts[3] = { wt2, wt3, wt4 };
        #pragma unroll
        for (int l = 0; l < 3; ++l) {
            float bj = sB[l + 1][0][lane];
            #pragma unroll
            for (int m = 0; m < NPW; ++m) acc[m] = bj;
            accum64(wts[l], h, acc);
            float gj = sB[l + 1][1][lane], btj = sB[l + 1][2][lane];
            #pragma unroll
            for (int m = 0; m < NPW; ++m) h[m] = ln_relu(acc[m], gj, btj);
        }

        #pragma unroll
        for (int m = 0; m < NPW; ++m) {
            int n = n0 + m;
            if (n < n_nodes) out[n * DD + lane] = h[m];
        }
    }
}

// ---------------------------------------------------------------------------
extern "C" void kernel_launch(void* const* d_in, const int* in_sizes, int n_in,
                              void* d_out, int out_size, void* d_ws, size_t ws_size,
                              hipStream_t stream) {
    const float* x   = (const float*)d_in[0];
    const float* e   = (const float*)d_in[1];
    const void*  idx = d_in[2];
    const float* W1 = (const float*)d_in[3],  *b1 = (const float*)d_in[4],
               * g1 = (const float*)d_in[5],  *bt1 = (const float*)d_in[6];
    const float* W2 = (const float*)d_in[7],  *b2 = (const float*)d_in[8],
               * g2 = (const float*)d_in[9],  *bt2 = (const float*)d_in[10];
    const float* W3 = (const float*)d_in[11], *b3 = (const float*)d_in[12],
               * g3 = (const float*)d_in[13], *bt3 = (const float*)d_in[14];
    const float* W4 = (const float*)d_in[15], *b4 = (const float*)d_in[16],
               * g4 = (const float*)d_in[17], *bt4 = (const float*)d_in[18];
    float* out = (float*)d_out;

    const int n_nodes = in_sizes[0] / DD;   // 50000
    const int n_edges = in_sizes[1];        // 1000000

    // ws layout: mi | mo | flag
    float* mi = (float*)d_ws;
    float* mo = mi + (size_t)n_nodes * DD;
    int* flag = (int*)(mo + (size_t)n_nodes * DD);

    // zero mi/mo (ws is poisoned 0xAA before every launch)
    hipMemsetAsync(d_ws, 0, (size_t)2 * n_nodes * DD * sizeof(float), stream);

    detect_idx_kernel<<<1, 256, 0, stream>>>(idx, flag, 4096, n_nodes);

    scatter_kernel<<<4096, 256, 0, stream>>>(x, e, idx, flag, mi, mo, n_edges);

    fused_mlp3<<<256, 1024, 0, stream>>>(
        mi, mo, x,
        W1, b1, g1, bt1, W2, b2, g2, bt2, W3, b3, g3, bt3, W4, b4, g4, bt4,
        out, n_nodes);
}

// Round 9
// 601.289 us; speedup vs baseline: 1.2884x; 1.1887x over previous
//
#include <hip/hip_runtime.h>

#define DD 64
#define EPSV 1e-5f

__device__ __forceinline__ float rlane_f(float v, int k) {
    return __int_as_float(__builtin_amdgcn_readlane(__float_as_int(v), k));
}

// ---------------------------------------------------------------------------
// Detect whether edge_index is int64 or int32 (JAX x64 flag ambiguity).
// ---------------------------------------------------------------------------
__global__ void detect_idx_kernel(const void* __restrict__ idx, int* __restrict__ flag,
                                  int nsample, int n_nodes) {
    const long long* p = (const long long*)idx;
    int bad = 0;
    for (int i = threadIdx.x; i < nsample; i += blockDim.x) {
        long long v = p[i];
        if (v < 0 || v >= (long long)n_nodes) bad = 1;
    }
    __shared__ int sbad;
    if (threadIdx.x == 0) sbad = 0;
    __syncthreads();
    if (bad) atomicOr(&sbad, 1);
    __syncthreads();
    if (threadIdx.x == 0) *flag = sbad ? 0 : 1;  // 1 => int64, 0 => int32
}

// ---------------------------------------------------------------------------
// CSR build: histogram -> scan -> fill
// ---------------------------------------------------------------------------
__global__ __launch_bounds__(256) void hist_kernel(
    const void* __restrict__ idx, const int* __restrict__ flag,
    int* __restrict__ cnt0, int* __restrict__ cnt1, int n_edges) {
    const bool is64 = (*flag != 0);
    const long long* p64 = (const long long*)idx;
    const int*       p32 = (const int*)idx;
    int tid = blockIdx.x * blockDim.x + threadIdx.x;
    int stride = gridDim.x * blockDim.x;
    for (int ed = tid; ed < n_edges; ed += stride) {
        int s, t;
        if (is64) { s = (int)p64[ed]; t = (int)p64[n_edges + ed]; }
        else      { s = p32[ed];      t = p32[n_edges + ed]; }
        atomicAdd(&cnt0[t], 1);
        atomicAdd(&cnt1[s], 1);
    }
}

// One block per direction; 1024 threads; int4-vectorized loads/stores.
// (Round-7 scan used 147 scalar mem insts/thread on only 2 CUs.)
#define SC 52  // per-thread chunk, multiple of 4; 1024*52 = 53248 >= 50001
__global__ __launch_bounds__(1024) void scan_kernel(
    const int* __restrict__ cnt0, const int* __restrict__ cnt1,
    int* __restrict__ offs0, int* __restrict__ offs1,
    int* __restrict__ cur0, int* __restrict__ cur1, int n) {
    const int* cnt = blockIdx.x ? cnt1 : cnt0;
    int* offs = blockIdx.x ? offs1 : offs0;
    int* cur  = blockIdx.x ? cur1  : cur0;
    const int t = threadIdx.x;
    const int base = t * SC;
    int m = n - base; if (m > SC) m = SC; if (m < 0) m = 0;

    int v[SC];
    int sum = 0;
    if (m == SC) {
        const int4* c4 = (const int4*)(cnt + base);
        #pragma unroll
        for (int i = 0; i < SC / 4; ++i) {
            int4 q = c4[i];
            v[4*i] = q.x; v[4*i+1] = q.y; v[4*i+2] = q.z; v[4*i+3] = q.w;
        }
        #pragma unroll
        for (int i = 0; i < SC; ++i) sum += v[i];
    } else {
        for (int i = 0; i < m; ++i) sum += cnt[base + i];
    }

    const int lane = t & 63, wid = t >> 6;
    int s = sum;
    #pragma unroll
    for (int d = 1; d < 64; d <<= 1) { int u = __shfl_up(s, d, 64); if (lane >= d) s += u; }

    __shared__ int wtot[16];
    if (lane == 63) wtot[wid] = s;
    __syncthreads();
    if (t < 16) {
        int w = wtot[t];
        int sw = w;
        #pragma unroll
        for (int d = 1; d < 16; d <<= 1) { int u = __shfl_up(sw, d, 64); if (t >= d) sw += u; }
        wtot[t] = sw - w;  // exclusive
    }
    __syncthreads();

    int run = wtot[wid] + (s - sum);  // exclusive prefix for this thread
    if (m == SC) {
        int4* o4 = (int4*)(offs + base);
        int4* c4w = (int4*)(cur + base);
        #pragma unroll
        for (int i = 0; i < SC / 4; ++i) {
            int4 q;
            q.x = run; run += v[4*i];
            q.y = run; run += v[4*i+1];
            q.z = run; run += v[4*i+2];
            q.w = run; run += v[4*i+3];
            o4[i] = q; c4w[i] = q;
        }
        if (base + SC == n) offs[n] = run;
    } else if (m > 0) {
        for (int i = 0; i < m; ++i) {
            int c = cnt[base + i];
            offs[base + i] = run;
            cur[base + i]  = run;
            run += c;
        }
        if (base + m == n) offs[n] = run;
    }
}

__global__ __launch_bounds__(256) void fill_kernel(
    const void* __restrict__ idx, const float* __restrict__ e, const int* __restrict__ flag,
    int* __restrict__ cur0, int* __restrict__ cur1,
    int2* __restrict__ pay0, int2* __restrict__ pay1, int n_edges) {
    const bool is64 = (*flag != 0);
    const long long* p64 = (const long long*)idx;
    const int*       p32 = (const int*)idx;
    int tid = blockIdx.x * blockDim.x + threadIdx.x;
    int stride = gridDim.x * blockDim.x;
    for (int ed = tid; ed < n_edges; ed += stride) {
        int s, t;
        if (is64) { s = (int)p64[ed]; t = (int)p64[n_edges + ed]; }
        else      { s = p32[ed];      t = p32[n_edges + ed]; }
        int wbits = __float_as_int(e[ed]);
        int p0 = atomicAdd(&cur0[t], 1);
        pay0[p0] = make_int2(s, wbits);
        int p1 = atomicAdd(&cur1[s], 1);
        pay1[p1] = make_int2(t, wbits);
    }
}

// ---------------------------------------------------------------------------
// Gather: one wave per (node, dir); payload batch-loaded, readlane-broadcast.
// ---------------------------------------------------------------------------
__global__ __launch_bounds__(256) void gather_kernel(
    const float* __restrict__ x,
    const int2* __restrict__ pay0, const int2* __restrict__ pay1,
    const int* __restrict__ offs0, const int* __restrict__ offs1,
    float* __restrict__ mi, float* __restrict__ mo, int n) {
    const int wid = threadIdx.x >> 6, lane = threadIdx.x & 63;
    const int gid = blockIdx.x * 4 + wid;
    if (gid >= 2 * n) return;
    const int dir = gid & 1, node = gid >> 1;
    const int* offs = dir ? offs1 : offs0;
    const int2* pay = dir ? pay1 : pay0;
    float* dst = dir ? mo : mi;

    const int o0 = offs[node], o1 = offs[node + 1];
    float acc = 0.0f;
    for (int b = o0; b < o1; b += 64) {
        int2 pl = make_int2(0, 0);
        if (b + lane < o1) pl = pay[b + lane];
        const int cnt = min(64, o1 - b);
        #pragma unroll 4
        for (int j = 0; j < cnt; ++j) {
            int src  = __builtin_amdgcn_readlane(pl.x, j);
            float w  = __int_as_float(__builtin_amdgcn_readlane(pl.y, j));
            acc = fmaf(w, x[src * DD + lane], acc);
        }
    }
    dst[node * DD + lane] = acc;
}

// ---------------------------------------------------------------------------
// Fallback atomic scatter (used only if ws too small for CSR).
// ---------------------------------------------------------------------------
__global__ __launch_bounds__(256) void scatter_kernel(
    const float* __restrict__ x, const float* __restrict__ e,
    const void* __restrict__ idx, const int* __restrict__ flag,
    float* __restrict__ mi, float* __restrict__ mo, int n_edges) {
    const int lane  = threadIdx.x & 63;
    const int slot  = (blockIdx.x * blockDim.x + threadIdx.x) >> 6;
    const int nslot = (gridDim.x * blockDim.x) >> 6;
    const bool is64 = (*flag != 0);
    const long long* p64 = (const long long*)idx;
    const int*       p32 = (const int*)idx;
    for (int ed = slot; ed < n_edges; ed += nslot) {
        int s, t;
        if (is64) { s = (int)p64[ed]; t = (int)p64[n_edges + ed]; }
        else      { s = p32[ed];      t = p32[n_edges + ed]; }
        float w  = e[ed];
        unsafeAtomicAdd(&mi[t * DD + lane], w * x[s * DD + lane]);
        unsafeAtomicAdd(&mo[s * DD + lane], w * x[t * DD + lane]);
    }
}

// ---------------------------------------------------------------------------
// Fused 4-layer MLP: h in registers (readlane broadcast), W^T in LDS
// (ds_read_b128 per 4 k). NPW=13 so ngroups=3847 <= 4096 waves: every wave
// runs at most ONE group (NPW=12 gave 4167 groups -> 71 waves ran 2 -> 2x tail).
// accum64 kept at unroll 2 (measured 211 us; unroll 4 measured ~296 us).
// ---------------------------------------------------------------------------
#define NPW 13
#define MWAVES 16
#define WT1_STRIDE 196  // 192+4 pad: 196 % 32 == 4 -> 2-way (free) on b128 reads
#define WT_STRIDE  68   // 64+4

template<int N>
__device__ __forceinline__ void accum64(const float4* __restrict__ wp,
                                        const float (&h)[N], float (&acc)[N]) {
    #pragma unroll 2
    for (int kb = 0; kb < 16; ++kb) {
        float4 w4 = wp[kb];
        int k0 = kb << 2;
        #pragma unroll
        for (int m = 0; m < N; ++m) acc[m] = fmaf(w4.x, rlane_f(h[m], k0), acc[m]);
        #pragma unroll
        for (int m = 0; m < N; ++m) acc[m] = fmaf(w4.y, rlane_f(h[m], k0 + 1), acc[m]);
        #pragma unroll
        for (int m = 0; m < N; ++m) acc[m] = fmaf(w4.z, rlane_f(h[m], k0 + 2), acc[m]);
        #pragma unroll
        for (int m = 0; m < N; ++m) acc[m] = fmaf(w4.w, rlane_f(h[m], k0 + 3), acc[m]);
    }
}

__device__ __forceinline__ float ln_relu(float v, float g, float bt) {
    float s = v;
    #pragma unroll
    for (int off = 32; off; off >>= 1) s += __shfl_xor(s, off, 64);
    float mu = s * (1.0f / 64.0f);
    float d = v - mu;
    float s2 = d * d;
    #pragma unroll
    for (int off = 32; off; off >>= 1) s2 += __shfl_xor(s2, off, 64);
    float r = d * rsqrtf(s2 * (1.0f / 64.0f) + EPSV) * g + bt;
    return fmaxf(r, 0.0f);
}

__global__ __launch_bounds__(1024) void fused_mlp2(
    const float* __restrict__ mi, const float* __restrict__ mo, const float* __restrict__ x,
    const float* __restrict__ W1, const float* __restrict__ b1, const float* __restrict__ g1, const float* __restrict__ bt1,
    const float* __restrict__ W2, const float* __restrict__ b2, const float* __restrict__ g2, const float* __restrict__ bt2,
    const float* __restrict__ W3, const float* __restrict__ b3, const float* __restrict__ g3, const float* __restrict__ bt3,
    const float* __restrict__ W4, const float* __restrict__ b4, const float* __restrict__ g4, const float* __restrict__ bt4,
    float* __restrict__ out, int n_nodes) {

    __shared__ float sWT1[64 * WT1_STRIDE];
    __shared__ float sWT2[64 * WT_STRIDE];
    __shared__ float sWT3[64 * WT_STRIDE];
    __shared__ float sWT4[64 * WT_STRIDE];
    __shared__ float sB[4][3][64];

    const int tid = threadIdx.x;
    for (int i = tid; i < 192 * 64; i += 1024) {
        int k = i >> 6, j = i & 63;
        sWT1[j * WT1_STRIDE + k] = W1[i];
    }
    for (int i = tid; i < 64 * 64; i += 1024) {
        int k = i >> 6, j = i & 63;
        sWT2[j * WT_STRIDE + k] = W2[i];
        sWT3[j * WT_STRIDE + k] = W3[i];
        sWT4[j * WT_STRIDE + k] = W4[i];
    }
    if (tid < 64) {
        int j = tid;
        sB[0][0][j] = b1[j]; sB[0][1][j] = g1[j]; sB[0][2][j] = bt1[j];
        sB[1][0][j] = b2[j]; sB[1][1][j] = g2[j]; sB[1][2][j] = bt2[j];
        sB[2][0][j] = b3[j]; sB[2][1][j] = g3[j]; sB[2][2][j] = bt3[j];
        sB[3][0][j] = b4[j]; sB[3][1][j] = g4[j]; sB[3][2][j] = bt4[j];
    }
    __syncthreads();

    const int wid = tid >> 6, lane = tid & 63;
    const int gw = blockIdx.x * MWAVES + wid;
    const int nw = gridDim.x * MWAVES;
    const float4* wt1 = (const float4*)&sWT1[lane * WT1_STRIDE];
    const float4* wt2 = (const float4*)&sWT2[lane * WT_STRIDE];
    const float4* wt3 = (const float4*)&sWT3[lane * WT_STRIDE];
    const float4* wt4 = (const float4*)&sWT4[lane * WT_STRIDE];

    const int ngroups = (n_nodes + NPW - 1) / NPW;
    for (int grp = gw; grp < ngroups; grp += nw) {
        const int n0 = grp * NPW;

        float hmi[NPW], hmo[NPW], hx[NPW];
        #pragma unroll
        for (int m = 0; m < NPW; ++m) {
            int n = n0 + m; if (n >= n_nodes) n = n_nodes - 1;
            hmi[m] = mi[n * DD + lane];
            hmo[m] = mo[n * DD + lane];
            hx[m]  = x[n * DD + lane];
        }

        float acc[NPW], h[NPW];

        // layer 1 (192-k)
        {
            float bj = sB[0][0][lane];
            #pragma unroll
            for (int m = 0; m < NPW; ++m) acc[m] = bj;
            accum64(wt1 +  0, hmi, acc);
            accum64(wt1 + 16, hmo, acc);
            accum64(wt1 + 32, hx,  acc);
            float gj = sB[0][1][lane], btj = sB[0][2][lane];
            #pragma unroll
            for (int m = 0; m < NPW; ++m) h[m] = ln_relu(acc[m], gj, btj);
        }

        // layers 2..4 (64-k)
        const float4* wts[3] = { wt2, wt3, wt4 };
        #pragma unroll
        for (int l = 0; l < 3; ++l) {
            float bj = sB[l + 1][0][lane];
            #pragma unroll
            for (int m = 0; m < NPW; ++m) acc[m] = bj;
            accum64(wts[l], h, acc);
            float gj = sB[l + 1][1][lane], btj = sB[l + 1][2][lane];
            #pragma unroll
            for (int m = 0; m < NPW; ++m) h[m] = ln_relu(acc[m], gj, btj);
        }

        #pragma unroll
        for (int m = 0; m < NPW; ++m) {
            int n = n0 + m;
            if (n < n_nodes) out[n * DD + lane] = h[m];
        }
    }
}

// ---------------------------------------------------------------------------
extern "C" void kernel_launch(void* const* d_in, const int* in_sizes, int n_in,
                              void* d_out, int out_size, void* d_ws, size_t ws_size,
                              hipStream_t stream) {
    const float* x   = (const float*)d_in[0];
    const float* e   = (const float*)d_in[1];
    const void*  idx = d_in[2];
    const float* W1 = (const float*)d_in[3],  *b1 = (const float*)d_in[4],
               * g1 = (const float*)d_in[5],  *bt1 = (const float*)d_in[6];
    const float* W2 = (const float*)d_in[7],  *b2 = (const float*)d_in[8],
               * g2 = (const float*)d_in[9],  *bt2 = (const float*)d_in[10];
    const float* W3 = (const float*)d_in[11], *b3 = (const float*)d_in[12],
               * g3 = (const float*)d_in[13], *bt3 = (const float*)d_in[14];
    const float* W4 = (const float*)d_in[15], *b4 = (const float*)d_in[16],
               * g4 = (const float*)d_in[17], *bt4 = (const float*)d_in[18];
    float* out = (float*)d_out;

    const int n_nodes = in_sizes[0] / DD;   // 50000
    const int n_edges = in_sizes[1];        // 1000000

    // ws layout, all sections 16B-aligned (scan uses int4):
    // mi | mo | flag(4 ints) | pay0 | pay1 | cnt0 | cnt1 | offs0 | offs1 | cur0 | cur1
    float* mi = (float*)d_ws;
    float* mo = mi + (size_t)n_nodes * DD;
    int*  flag = (int*)(mo + (size_t)n_nodes * DD);
    char* p = (char*)(flag + 4);  // 16B
    const int offs_pad = (n_nodes + 1 + 3) & ~3;  // 50004: keeps following arrays 16B-aligned
    int2* pay0 = (int2*)p;            p += (size_t)n_edges * sizeof(int2);
    int2* pay1 = (int2*)p;            p += (size_t)n_edges * sizeof(int2);
    int* cnt0  = (int*)p;             p += (size_t)n_nodes * 4;
    int* cnt1  = (int*)p;             p += (size_t)n_nodes * 4;
    int* offs0 = (int*)p;             p += (size_t)offs_pad * 4;
    int* offs1 = (int*)p;             p += (size_t)offs_pad * 4;
    int* cur0  = (int*)p;             p += (size_t)n_nodes * 4;
    int* cur1  = (int*)p;             p += (size_t)n_nodes * 4;
    const size_t need = (size_t)(p - (char*)d_ws);

    detect_idx_kernel<<<1, 256, 0, stream>>>(idx, flag, 4096, n_nodes);

    if (ws_size >= need) {
        // CSR path: histogram -> scan -> fill -> gather (no f32 atomics)
        hipMemsetAsync(cnt0, 0, (size_t)2 * n_nodes * 4, stream);  // cnt0|cnt1 contiguous
        hist_kernel<<<2048, 256, 0, stream>>>(idx, flag, cnt0, cnt1, n_edges);
        scan_kernel<<<2, 1024, 0, stream>>>(cnt0, cnt1, offs0, offs1, cur0, cur1, n_nodes);
        fill_kernel<<<2048, 256, 0, stream>>>(idx, e, flag, cur0, cur1, pay0, pay1, n_edges);
        const int nblocks = (2 * n_nodes + 3) / 4;
        gather_kernel<<<nblocks, 256, 0, stream>>>(x, pay0, pay1, offs0, offs1, mi, mo, n_nodes);
    } else {
        // fallback: atomic scatter (measured 408 us)
        hipMemsetAsync(d_ws, 0, (size_t)2 * n_nodes * DD * sizeof(float), stream);
        scatter_kernel<<<4096, 256, 0, stream>>>(x, e, idx, flag, mi, mo, n_edges);
    }

    fused_mlp2<<<256, 1024, 0, stream>>>(
        mi, mo, x,
        W1, b1, g1, bt1, W2, b2, g2, bt2, W3, b3, g3, bt3, W4, b4, g4, bt4,
        out, n_nodes);
}